// Round 4
// baseline (561.628 us; speedup 1.0000x reference)
//
#include <hip/hip_runtime.h>
#include <cstdint>
#include <cstddef>

typedef __bf16 bf16_t;
typedef __attribute__((ext_vector_type(8))) __bf16 bf16x8;
typedef __attribute__((ext_vector_type(4))) __bf16 bf16x4;
typedef __attribute__((ext_vector_type(4))) float floatx4;

#define NB 32
#define NW 168
#define NM 2048
#define NHID 128
#define NBW (NB * NW)  // 5376

#define GLOAD_LDS16(g, l)                                          \
  __builtin_amdgcn_global_load_lds(                                \
      (const __attribute__((address_space(1))) void*)(g),          \
      (__attribute__((address_space(3))) void*)(l), 16, 0, 0)

// elementwise fp32 -> bf16 cast, n4 = n/4
__global__ void cast_bf16_kernel(const float* __restrict__ in, bf16_t* __restrict__ out, int n4) {
  int stride = gridDim.x * blockDim.x;
  for (int i = blockIdx.x * blockDim.x + threadIdx.x; i < n4; i += stride) {
    float4 v = ((const float4*)in)[i];
    bf16x4 o = {(bf16_t)v.x, (bf16_t)v.y, (bf16_t)v.z, (bf16_t)v.w};
    ((bf16x4*)out)[i] = o;
  }
}

// out[c][r] = (bf16) in[r][c]; R, C multiples of 64. fp32 in.
__global__ void transpose_cast_kernel(const float* __restrict__ in, bf16_t* __restrict__ out,
                                      int R, int C) {
  __shared__ float tile[64][65];
  int r0 = blockIdx.y * 64, c0 = blockIdx.x * 64;
  int t = threadIdx.x;
  int tr = t >> 4, tc4 = (t & 15) * 4;
#pragma unroll
  for (int p = 0; p < 4; ++p) {
    int row = p * 16 + tr;
    float4 v = *(const float4*)(in + (size_t)(r0 + row) * C + c0 + tc4);
    tile[row][tc4 + 0] = v.x;
    tile[row][tc4 + 1] = v.y;
    tile[row][tc4 + 2] = v.z;
    tile[row][tc4 + 3] = v.w;
  }
  __syncthreads();
#pragma unroll
  for (int p = 0; p < 4; ++p) {
    int c = p * 16 + tr;
    bf16x4 o = {(bf16_t)tile[tc4 + 0][c], (bf16_t)tile[tc4 + 1][c],
                (bf16_t)tile[tc4 + 2][c], (bf16_t)tile[tc4 + 3][c]};
    *(bf16x4*)(out + (size_t)(c0 + c) * R + r0 + tc4) = o;
  }
}

// Fused x prep: read x [(bw)][m] fp32 once; write Xb [(bw)][m] bf16 (cast) and
// XT [m][(bw)] bf16 (transpose). 64x64 tiles.
__global__ void prep_x_kernel(const float* __restrict__ x, bf16_t* __restrict__ Xb,
                              bf16_t* __restrict__ XT) {
  __shared__ float tile[64][65];
  const int R = NBW, C = NM;
  int r0 = blockIdx.y * 64, c0 = blockIdx.x * 64;
  int t = threadIdx.x;
  int tr = t >> 4, tc4 = (t & 15) * 4;
#pragma unroll
  for (int p = 0; p < 4; ++p) {
    int row = p * 16 + tr;
    float4 v = *(const float4*)(x + (size_t)(r0 + row) * C + c0 + tc4);
    tile[row][tc4 + 0] = v.x;
    tile[row][tc4 + 1] = v.y;
    tile[row][tc4 + 2] = v.z;
    tile[row][tc4 + 3] = v.w;
    bf16x4 o = {(bf16_t)v.x, (bf16_t)v.y, (bf16_t)v.z, (bf16_t)v.w};
    *(bf16x4*)(Xb + (size_t)(r0 + row) * C + c0 + tc4) = o;
  }
  __syncthreads();
#pragma unroll
  for (int p = 0; p < 4; ++p) {
    int c = p * 16 + tr;
    bf16x4 o = {(bf16_t)tile[tc4 + 0][c], (bf16_t)tile[tc4 + 1][c],
                (bf16_t)tile[tc4 + 2][c], (bf16_t)tile[tc4 + 3][c]};
    *(bf16x4*)(XT + (size_t)(c0 + c) * R + r0 + tc4) = o;
  }
}

// Multi-job NT GEMM, K=2048, all leading dims 2048, async LDS staging (m97).
// MODE 0: main 672 blk (M=5376,N=2048): C=Tt1 + Ct0=XT1 | aux 256 blk: Caux=L^2
// MODE 1: main 1344 blk (M=5376,N=4096): nh0 -> Ct0=XT2; nh1 -> C=Tt3 + Ct1=XT3
//         | aux 256 blk: Caux=L^3
// MODE 2: main 2016 blk (M=5376,N=6144): nh -> Ct0/Ct1/Ct2 = XT4/XT5/XT6
template <int MODE>
__global__ void gemm_multi(const bf16_t* __restrict__ A, const bf16_t* __restrict__ Bt,
                           const bf16_t* __restrict__ A2, const bf16_t* __restrict__ Bt2,
                           bf16_t* __restrict__ C, bf16_t* __restrict__ Caux,
                           bf16_t* __restrict__ Ct0, bf16_t* __restrict__ Ct1,
                           bf16_t* __restrict__ Ct2) {
  constexpr int NBX = (MODE == 0) ? 16 : (MODE == 1) ? 32 : 48;
  constexpr int NMAIN = 42 * NBX;
  __shared__ bf16_t As[128 * 32];
  __shared__ bf16_t Bs[128 * 32];
  int bid = blockIdx.x;
  int tid = threadIdx.x;
  const bf16_t* Ap;
  const bf16_t* Btp;
  int m0, n0;
  bool aux = false;
  if (MODE < 2 && bid >= NMAIN) {
    aux = true;
    int l = bid - NMAIN;
    m0 = (l >> 4) * 128;
    n0 = (l & 15) * 128;
    Ap = A2;
    Btp = Bt2;
  } else {
    m0 = (bid / NBX) * 128;
    n0 = (bid % NBX) * 128;
    Ap = A;
    Btp = Bt;
  }
  int lane = tid & 63, wv = tid >> 6;
  int wm = wv >> 1, wn = wv & 1;
  int quad = lane >> 4, l15 = lane & 15;

  // staging: wave wv handles chunks [wv*128, wv*128+128) per buffer; 2 calls of 64
  int p0 = wv * 128 + lane;
  int p1 = p0 + 64;
  int row0 = p0 >> 2, kc0 = (p0 & 3) ^ ((p0 >> 3) & 3);
  int row1 = p1 >> 2, kc1 = (p1 & 3) ^ ((p1 >> 3) & 3);
  const bf16_t* a0p = Ap + (size_t)(m0 + row0) * 2048 + kc0 * 8;
  const bf16_t* a1p = Ap + (size_t)(m0 + row1) * 2048 + kc1 * 8;
  const bf16_t* b0p = Btp + (size_t)(n0 + row0) * 2048 + kc0 * 8;
  const bf16_t* b1p = Btp + (size_t)(n0 + row1) * 2048 + kc1 * 8;
  bf16_t* As_d0 = As + (size_t)(wv * 128) * 8;
  bf16_t* As_d1 = As + (size_t)(wv * 128 + 64) * 8;
  bf16_t* Bs_d0 = Bs + (size_t)(wv * 128) * 8;
  bf16_t* Bs_d1 = Bs + (size_t)(wv * 128 + 64) * 8;

  // fragment-read swizzle: kc position = quad ^ ((l15>>1)&3)
  int swz = (l15 >> 1) & 3;
  int kpos = (quad ^ swz) * 8;

  floatx4 zero4 = {0.f, 0.f, 0.f, 0.f};
  floatx4 acc[4][4];
#pragma unroll
  for (int mi = 0; mi < 4; ++mi)
#pragma unroll
    for (int ni = 0; ni < 4; ++ni) acc[mi][ni] = zero4;

  for (int kb = 0; kb < 2048; kb += 32) {
    GLOAD_LDS16(a0p + kb, As_d0);
    GLOAD_LDS16(a1p + kb, As_d1);
    GLOAD_LDS16(b0p + kb, Bs_d0);
    GLOAD_LDS16(b1p + kb, Bs_d1);
    __syncthreads();
    bf16x8 af[4], bf[4];
#pragma unroll
    for (int mi = 0; mi < 4; ++mi)
      af[mi] = *(const bf16x8*)(As + (wm * 64 + mi * 16 + l15) * 32 + kpos);
#pragma unroll
    for (int ni = 0; ni < 4; ++ni)
      bf[ni] = *(const bf16x8*)(Bs + (wn * 64 + ni * 16 + l15) * 32 + kpos);
#pragma unroll
    for (int mi = 0; mi < 4; ++mi)
#pragma unroll
      for (int ni = 0; ni < 4; ++ni)
        acc[mi][ni] = __builtin_amdgcn_mfma_f32_16x16x32_bf16(af[mi], bf[ni], acc[mi][ni], 0, 0, 0);
    __syncthreads();
  }

  // epilogue: select outputs per n-half (block-uniform)
  int nh = n0 >> 11;
  int n0l = n0 - (nh << 11);
  bf16_t* Ctp = nullptr;
  bf16_t* Cp = nullptr;
  if (aux) {
    Cp = Caux;
  } else {
    Ctp = (nh == 0) ? Ct0 : (nh == 1) ? Ct1 : Ct2;
    if (MODE == 0) Cp = C;
    if (MODE == 1 && nh == 1) Cp = C;
  }
#pragma unroll
  for (int mi = 0; mi < 4; ++mi) {
#pragma unroll
    for (int ni = 0; ni < 4; ++ni) {
      int col_l = n0l + wn * 64 + ni * 16 + l15;
      int rowb = m0 + wm * 64 + mi * 16 + quad * 4;
      bf16x4 tv;
#pragma unroll
      for (int r = 0; r < 4; ++r) tv[r] = (bf16_t)acc[mi][ni][r];
      if (Ctp) *(bf16x4*)(Ctp + (size_t)col_l * NBW + rowb) = tv;
      if (Cp) {
#pragma unroll
        for (int r = 0; r < 4; ++r) Cp[(size_t)(rowb + r) * 2048 + col_l] = tv[r];
      }
    }
  }
}

// Multi-hop fused MLP + score. blockIdx: sub = bx>>9 selects (T, hop);
// r0 = (bx&511)*128 rows (r = m*32+b). K=168 padded to 192 (W1 LDS pad = 0).
// score = sum_h relu(H+b1)*W2 + b2 -> atomicAdd(out[b*NM+m]).
__global__ void mlp_multi(const bf16_t* __restrict__ T0, const bf16_t* __restrict__ T1,
                          const bf16_t* __restrict__ T2, const bf16_t* __restrict__ W1b,
                          const float* __restrict__ b1, const float* __restrict__ W2,
                          const float* __restrict__ b2, float* __restrict__ out, int hop_base) {
  __shared__ bf16_t Bs[24 * 128 * 8];  // 48 KB: chunk (kc,h_pos) at (kc*128+h_pos)*8
  __shared__ float sred[4][64];
  int sub = blockIdx.x >> 9;
  int r0 = (blockIdx.x & 511) * 128;
  int hop = hop_base + sub;
  const bf16_t* T = (sub == 0) ? T0 : (sub == 1) ? T1 : T2;
  const bf16_t* Wh = W1b + (size_t)hop * NHID * NW;
  const float* b1h = b1 + hop * NHID;
  const float* w2h = W2 + hop * NHID;
  int tid = threadIdx.x;
  int lane = tid & 63, wv = tid >> 6;
  int wm = wv >> 1, wn = wv & 1;
  int quad = lane >> 4, l15 = lane & 15;

  // zero the pad chunks [2688, 3072) = kc 21..23
  for (int c = 2688 + tid; c < 3072; c += 256) {
    int4 z = {0, 0, 0, 0};
    *(int4*)(Bs + (size_t)c * 8) = z;
  }
  // stage 2688 valid chunks; LDS pos c -> kc=c>>7, h = (c&127) ^ ((kc&3)<<2)
  for (int i = 0; i < 11; ++i) {
    int c = i * 256 + tid;
    if (c < 2688) {  // 2688 = 42 full waves
      int kc = c >> 7;
      int h = (c & 127) ^ ((kc & 3) << 2);
      GLOAD_LDS16(Wh + (size_t)h * NW + kc * 8, Bs + (size_t)(i * 256 + wv * 64) * 8);
    }
  }

  // A row pointers (per mi): row index R = r0 + wm*64 + mi*16 + l15
  const bf16_t* arow[4];
#pragma unroll
  for (int mi = 0; mi < 4; ++mi) {
    int R = r0 + wm * 64 + mi * 16 + l15;
    arow[mi] = T + (size_t)(R >> 5) * NBW + (size_t)(R & 31) * NW + quad * 8;
  }

  floatx4 zero4 = {0.f, 0.f, 0.f, 0.f};
  floatx4 acc[4][4];
#pragma unroll
  for (int mi = 0; mi < 4; ++mi)
#pragma unroll
    for (int ni = 0; ni < 4; ++ni) acc[mi][ni] = zero4;

  __syncthreads();  // staging (incl. async loads) complete

#pragma unroll
  for (int kb = 0; kb < 192; kb += 32) {
    int kc = (kb >> 3) + quad;
    bf16x8 af[4], bf[4];
#pragma unroll
    for (int mi = 0; mi < 4; ++mi)
      af[mi] = *(const bf16x8*)(arow[mi] + kb);  // k>=168 reads garbage; B pad=0
#pragma unroll
    for (int ni = 0; ni < 4; ++ni) {
      int hpos = (wn * 64 + ni * 16 + l15) ^ ((kc & 3) << 2);
      bf[ni] = *(const bf16x8*)(Bs + (size_t)(kc * 128 + hpos) * 8);
    }
#pragma unroll
    for (int mi = 0; mi < 4; ++mi)
#pragma unroll
      for (int ni = 0; ni < 4; ++ni)
        acc[mi][ni] = __builtin_amdgcn_mfma_f32_16x16x32_bf16(af[mi], bf[ni], acc[mi][ni], 0, 0, 0);
  }

  // epilogue: relu(H + b1) dot W2 per row
  float part[4][4];
#pragma unroll
  for (int mi = 0; mi < 4; ++mi)
#pragma unroll
    for (int r = 0; r < 4; ++r) part[mi][r] = 0.f;
#pragma unroll
  for (int ni = 0; ni < 4; ++ni) {
    int col = wn * 64 + ni * 16 + l15;
    float b1v = b1h[col];
    float w2v = w2h[col];
#pragma unroll
    for (int mi = 0; mi < 4; ++mi)
#pragma unroll
      for (int r = 0; r < 4; ++r) {
        float h = acc[mi][ni][r] + b1v;
        h = h > 0.f ? h : 0.f;
        part[mi][r] += h * w2v;
      }
  }
#pragma unroll
  for (int off = 1; off < 16; off <<= 1)
#pragma unroll
    for (int mi = 0; mi < 4; ++mi)
#pragma unroll
      for (int r = 0; r < 4; ++r) part[mi][r] += __shfl_xor(part[mi][r], off);
  if (l15 == 0) {
#pragma unroll
    for (int mi = 0; mi < 4; ++mi)
#pragma unroll
      for (int r = 0; r < 4; ++r) sred[wv][mi * 16 + quad * 4 + r] = part[mi][r];
  }
  __syncthreads();
  if (tid < 128) {
    int half = tid >> 6;
    int lr = tid & 63;
    float v = sred[half * 2][lr] + sred[half * 2 + 1][lr] + b2[hop];
    int R = r0 + half * 64 + lr;
    int idx = (R & 31) * NM + (R >> 5);  // out[b*M + m]
    atomicAdd(out + idx, v);
  }
}

extern "C" void kernel_launch(void* const* d_in, const int* in_sizes, int n_in,
                              void* d_out, int out_size, void* d_ws, size_t ws_size,
                              hipStream_t stream) {
  const float* x = (const float*)d_in[0];
  const float* L = (const float*)d_in[1];
  const float* W1 = (const float*)d_in[2];
  const float* b1 = (const float*)d_in[3];
  const float* W2 = (const float*)d_in[4];
  const float* b2 = (const float*)d_in[5];
  float* out = (float*)d_out;

  char* ws = (char*)d_ws;
  size_t off = 0;
  auto walloc = [&](size_t bytes) -> void* {
    off = (off + 255) & ~(size_t)255;
    void* p = ws + off;
    off += bytes;
    return p;
  };
  const size_t SZ_L = (size_t)NM * NM * 2;      // 8.4 MB
  const size_t SZ_T = (size_t)NBW * NM * 2;     // 22 MB
  bf16_t* W1b = (bf16_t*)walloc((size_t)7 * NHID * NW * 2);
  bf16_t* Lstack = (bf16_t*)walloc(3 * SZ_L);   // [L; L^2; L^3]
  bf16_t* Lb = Lstack;
  bf16_t* L2b = Lstack + (size_t)NM * NM;
  bf16_t* L3b = Lstack + 2 * (size_t)NM * NM;
  bf16_t* Ltb = (bf16_t*)walloc(SZ_L);          // L^T; dead after D2
  bf16_t* Tt1 = (bf16_t*)walloc(SZ_T);          // dead after D2
  bf16_t* XTp2 = (bf16_t*)((char*)Ltb);         // overlays [Ltb,Tt1]; born in D3
  bf16_t* Xb = (bf16_t*)walloc(SZ_T);           // dead after D1
  bf16_t* Tt3 = Xb;                             // overlays Xb; born in D2
  bf16_t* XTp0 = (bf16_t*)walloc(SZ_T);
  bf16_t* XTp1 = (bf16_t*)walloc(SZ_T);
  (void)ws_size; (void)in_sizes; (void)n_in;

  hipMemsetAsync(out, 0, (size_t)out_size * 4, stream);
  prep_x_kernel<<<dim3(NM / 64, NBW / 64), dim3(256), 0, stream>>>(x, Xb, XTp0);
  cast_bf16_kernel<<<dim3(1024), dim3(256), 0, stream>>>(L, Lb, NM * NM / 4);
  transpose_cast_kernel<<<dim3(NM / 64, NM / 64), dim3(256), 0, stream>>>(L, Ltb, NM, NM);
  cast_bf16_kernel<<<dim3(64), dim3(256), 0, stream>>>(W1, W1b, 7 * NHID * NW / 4);

  // D1: T1 = X Lt (672 blk) || L2 = L*L (256 blk)
  gemm_multi<0><<<dim3(928), dim3(256), 0, stream>>>(
      Xb, Lb, Lb, Ltb, Tt1, L2b, XTp1, nullptr, nullptr);
  // hops 0 (XTp0) and 1 (XTp1)
  mlp_multi<<<dim3(1024), dim3(256), 0, stream>>>(XTp0, XTp1, nullptr, W1b, b1, W2, b2, out, 0);
  // D2: [T2|T3] = T1*[L;L2]t (1344 blk) || L3 = L2*L (256 blk)
  gemm_multi<1><<<dim3(1600), dim3(256), 0, stream>>>(
      Tt1, Lstack, L2b, Ltb, Tt3, L3b, XTp0, XTp1, nullptr);
  // hops 2 (XTp0) and 3 (XTp1)
  mlp_multi<<<dim3(1024), dim3(256), 0, stream>>>(XTp0, XTp1, nullptr, W1b, b1, W2, b2, out, 2);
  // D3: [T4|T5|T6] = T3*[L;L2;L3]t (2016 blk)
  gemm_multi<2><<<dim3(2016), dim3(256), 0, stream>>>(
      Tt3, Lstack, nullptr, nullptr, nullptr, nullptr, XTp0, XTp1, XTp2);
  // hops 4,5,6
  mlp_multi<<<dim3(1536), dim3(256), 0, stream>>>(XTp0, XTp1, XTp2, W1b, b1, W2, b2, out, 4);
}